// Round 10
// baseline (608.882 us; speedup 1.0000x reference)
//
#include <hip/hip_runtime.h>

#define NN 100000
#define NE 1600000
#define DF 32
#define DEPTH 10
#define LSTRIDE ((DEPTH + 1) * DF) /* 352 floats per node in d_out */
#define SCAN_BLOCKS 256
#define SCAN_T 256
#define PAD 4
#define PADM (~(PAD - 1))

// zero cnt (n ints) + cpack (cp4 int4s) in one fast kernel
__global__ void fill_k(int* __restrict__ cnt, int4* __restrict__ cpack4,
                       int n4_cnt, long long cp4) {
    long long i = (long long)blockIdx.x * blockDim.x + threadIdx.x;
    long long stride = (long long)gridDim.x * blockDim.x;
    const int4 z = make_int4(0, 0, 0, 0);
    for (long long j = i; j < cp4; j += stride) cpack4[j] = z;
    int4* c4 = (int4*)cnt;
    for (long long j = i; j < n4_cnt; j += stride) c4[j] = z;
}

// histogram + per-edge rank within its row (atomic result was free)
__global__ void hist_k(const int* __restrict__ row, int* __restrict__ cnt,
                       int* __restrict__ prank, int e) {
    int i = blockIdx.x * blockDim.x + threadIdx.x;
    int stride = gridDim.x * blockDim.x;
    for (; i < e; i += stride) {
        int r = __builtin_nontemporal_load(&row[i]);
        prank[i] = atomicAdd(&cnt[r], 1);
    }
}

// --- multi-block scan over PADDED counts ((cnt+PAD-1)&PADM) ---
__global__ void scan_partial_k(const int* __restrict__ cnt, int* __restrict__ bsum,
                               int n, int chunk) {
    __shared__ int red[SCAN_T];
    int b = blockIdx.x, t = threadIdx.x;
    int beg = b * chunk, end = min(n, beg + chunk);
    int s = 0;
    for (int i = beg + t; i < end; i += SCAN_T) s += (cnt[i] + PAD - 1) & PADM;
    red[t] = s;
    __syncthreads();
    for (int off = SCAN_T / 2; off; off >>= 1) {
        if (t < off) red[t] += red[t + off];
        __syncthreads();
    }
    if (t == 0) bsum[b] = red[0];
}

__global__ void scan_bsum_k(const int* __restrict__ bsum, int* __restrict__ boff) {
    __shared__ int s[SCAN_BLOCKS];
    int t = threadIdx.x;
    s[t] = bsum[t];
    __syncthreads();
    for (int off = 1; off < SCAN_BLOCKS; off <<= 1) {
        int v = (t >= off) ? s[t - off] : 0;
        __syncthreads();
        s[t] += v;
        __syncthreads();
    }
    boff[t] = (t == 0) ? 0 : s[t - 1];
}

// emit padded-exclusive-prefix rowptr; also compute dinv from real cnt (fused).
__global__ void scan_emit_k(const int* __restrict__ cnt, const int* __restrict__ boff,
                            int* __restrict__ rowptr, float* __restrict__ dinv,
                            int n, int chunk) {
    __shared__ int tile[SCAN_T];
    int b = blockIdx.x, t = threadIdx.x;
    int beg = b * chunk, end = min(n, beg + chunk);
    int run = boff[b];
    for (int base = beg; base < end; base += SCAN_T) {
        int i = base + t;
        int creal = (i < end) ? cnt[i] : 0;
        int c = (creal + PAD - 1) & PADM;
        tile[t] = c;
        __syncthreads();
        for (int off = 1; off < SCAN_T; off <<= 1) {
            int v = (t >= off) ? tile[t - off] : 0;
            __syncthreads();
            tile[t] += v;
            __syncthreads();
        }
        if (i < end) {
            rowptr[i] = run + tile[t] - c; // exclusive prefix of padded counts
            float d = (creal == 0) ? 1.0f : (float)creal;
            dinv[i] = rsqrtf(d);
        }
        run += tile[SCAN_T - 1];
        __syncthreads();
    }
    if (b == gridDim.x - 1 && t == 0) rowptr[n] = run;
}

// atomic-free scatter: pos = rowptr[row] + prank (pad slots stay zero from fill_k).
// Plain store — NT store on random 8B writes regressed 65µs (R9).
__global__ void scatter_k(const int* __restrict__ row, const int* __restrict__ col,
                          const float* __restrict__ ea, const float* __restrict__ dinv,
                          const int* __restrict__ rowptr, const int* __restrict__ prank,
                          unsigned long long* __restrict__ cpack, int e) {
    int i = blockIdx.x * blockDim.x + threadIdx.x;
    int stride = gridDim.x * blockDim.x;
    for (; i < e; i += stride) {
        int r = __builtin_nontemporal_load(&row[i]);
        int c = __builtin_nontemporal_load(&col[i]);
        float a = __builtin_nontemporal_load(&ea[i]);
        int pr = __builtin_nontemporal_load(&prank[i]);
        float v = dinv[r] * a * dinv[c];
        int pos = rowptr[r] + pr;
        cpack[pos] = ((unsigned long long)(unsigned)__float_as_int(v) << 32) | (unsigned)c;
    }
}

// out[node][0][:] = x[node][:]  (float4 vectorized)
__global__ void copy_k(const float* __restrict__ x, float* __restrict__ out, int n) {
    int t = blockIdx.x * blockDim.x + threadIdx.x; // n*8 float4s
    if (t < n * 8) {
        int node = t >> 3, q = t & 7;
        ((float4*)out)[(size_t)node * (LSTRIDE / 4) + q] = ((const float4*)x)[t];
    }
}

// one 32-lane group per row; lane = feature; branch-free unroll-4 over pad-4 CSR.
__global__ __launch_bounds__(256) void spmm_k(const int* __restrict__ rowptr,
                                              const unsigned long long* __restrict__ cpack,
                                              const float* __restrict__ pe,
                                              float* __restrict__ out, int n, int layer) {
    int gid = blockIdx.x * 8 + (threadIdx.x >> 5);
    int lane = threadIdx.x & 31;
    if (gid >= n) return;
    float alpha = tanhf(pe[layer]); // BASE_ALPHA = 1
    const float* __restrict__ hsrc = out + (size_t)layer * DF + lane;
    int beg = rowptr[gid], end = rowptr[gid + 1]; // multiple of 4 apart
    float acc = 0.f;
    for (int base = beg; base < end; base += 4) {
        unsigned long long p[4];
#pragma unroll
        for (int u = 0; u < 4; ++u) p[u] = __builtin_nontemporal_load(&cpack[base + u]);
        float h[4];
#pragma unroll
        for (int u = 0; u < 4; ++u)
            h[u] = hsrc[(unsigned)(p[u] & 0xFFFFFFFFu) * (unsigned)LSTRIDE];
#pragma unroll
        for (int u = 0; u < 4; ++u)
            acc = fmaf(__uint_as_float((unsigned)(p[u] >> 32)), h[u], acc);
    }
    out[(size_t)gid * LSTRIDE + (layer + 1) * DF + lane] = alpha * acc;
}

extern "C" void kernel_launch(void* const* d_in, const int* in_sizes, int n_in,
                              void* d_out, int out_size, void* d_ws, size_t ws_size,
                              hipStream_t stream) {
    const float* x  = (const float*)d_in[0];
    const int*   ei = (const int*)d_in[1];
    const float* ea = (const float*)d_in[2];
    const float* pe = (const float*)d_in[3];
    float* out = (float*)d_out;

    const int n = in_sizes[0] / DF;   // 100000
    const int e = in_sizes[2];        // 1600000
    const int* row = ei;
    const int* col = ei + e;

    // workspace layout
    int*   cnt    = (int*)d_ws;               // n  (16B-aligned: ws base)
    int*   rowptr = cnt + n;                  // n+1
    float* dinv   = (float*)(rowptr + n + 1); // n
    int*   bsum   = (int*)(dinv + n);         // SCAN_BLOCKS
    int*   boff   = bsum + SCAN_BLOCKS;       // SCAN_BLOCKS
    int*   prank  = boff + SCAN_BLOCKS;       // e
    size_t off = ((size_t)(prank + e) - (size_t)d_ws + 15) & ~(size_t)15;
    unsigned long long* cpack = (unsigned long long*)((char*)d_ws + off); // e + (PAD-1)n

    const long long cpack_entries = (long long)e + (long long)(PAD - 1) * n;
    const long long cp4 = (cpack_entries * 2 + 3) / 4; // int4 count covering cpack
    const int n4_cnt = (n + 3) / 4;

    const int chunk = (n + SCAN_BLOCKS - 1) / SCAN_BLOCKS;

    fill_k<<<2048, 256, 0, stream>>>(cnt, (int4*)cpack, n4_cnt, cp4);
    hist_k<<<2048, 256, 0, stream>>>(row, cnt, prank, e);
    scan_partial_k<<<SCAN_BLOCKS, SCAN_T, 0, stream>>>(cnt, bsum, n, chunk);
    scan_bsum_k<<<1, SCAN_BLOCKS, 0, stream>>>(bsum, boff);
    scan_emit_k<<<SCAN_BLOCKS, SCAN_T, 0, stream>>>(cnt, boff, rowptr, dinv, n, chunk);
    scatter_k<<<2048, 256, 0, stream>>>(row, col, ea, dinv, rowptr, prank, cpack, e);
    copy_k<<<(n * 8 + 255) / 256, 256, 0, stream>>>(x, out, n);

    for (int L = 0; L < DEPTH; ++L) {
        spmm_k<<<(n + 7) / 8, 256, 0, stream>>>(rowptr, cpack, pe, out, n, L);
    }
}

// Round 11
// 534.064 us; speedup vs baseline: 1.1401x; 1.1401x over previous
//
#include <hip/hip_runtime.h>

#define NN 100000
#define NE 1600000
#define DF 32
#define DEPTH 10
#define LSTRIDE ((DEPTH + 1) * DF) /* 352 floats per node in d_out */
#define SCAN_BLOCKS 256
#define SCAN_T 256
#define PAD 8
#define PADM (~(PAD - 1))

// zero cnt (n ints) + cpack (cp4 int4s) in one fast kernel
__global__ void fill_k(int* __restrict__ cnt, int4* __restrict__ cpack4,
                       int n4_cnt, long long cp4) {
    long long i = (long long)blockIdx.x * blockDim.x + threadIdx.x;
    long long stride = (long long)gridDim.x * blockDim.x;
    const int4 z = make_int4(0, 0, 0, 0);
    for (long long j = i; j < cp4; j += stride) cpack4[j] = z;
    int4* c4 = (int4*)cnt;
    for (long long j = i; j < n4_cnt; j += stride) c4[j] = z;
}

// histogram + per-edge rank within its row (atomic result was free)
__global__ void hist_k(const int* __restrict__ row, int* __restrict__ cnt,
                       int* __restrict__ prank, int e) {
    int i = blockIdx.x * blockDim.x + threadIdx.x;
    int stride = gridDim.x * blockDim.x;
    for (; i < e; i += stride) {
        int r = __builtin_nontemporal_load(&row[i]);
        prank[i] = atomicAdd(&cnt[r], 1);
    }
}

// --- multi-block scan over PADDED counts ((cnt+PAD-1)&PADM) ---
__global__ void scan_partial_k(const int* __restrict__ cnt, int* __restrict__ bsum,
                               int n, int chunk) {
    __shared__ int red[SCAN_T];
    int b = blockIdx.x, t = threadIdx.x;
    int beg = b * chunk, end = min(n, beg + chunk);
    int s = 0;
    for (int i = beg + t; i < end; i += SCAN_T) s += (cnt[i] + PAD - 1) & PADM;
    red[t] = s;
    __syncthreads();
    for (int off = SCAN_T / 2; off; off >>= 1) {
        if (t < off) red[t] += red[t + off];
        __syncthreads();
    }
    if (t == 0) bsum[b] = red[0];
}

__global__ void scan_bsum_k(const int* __restrict__ bsum, int* __restrict__ boff) {
    __shared__ int s[SCAN_BLOCKS];
    int t = threadIdx.x;
    s[t] = bsum[t];
    __syncthreads();
    for (int off = 1; off < SCAN_BLOCKS; off <<= 1) {
        int v = (t >= off) ? s[t - off] : 0;
        __syncthreads();
        s[t] += v;
        __syncthreads();
    }
    boff[t] = (t == 0) ? 0 : s[t - 1];
}

// emit padded-exclusive-prefix rowptr; also compute dinv from real cnt (fused).
__global__ void scan_emit_k(const int* __restrict__ cnt, const int* __restrict__ boff,
                            int* __restrict__ rowptr, float* __restrict__ dinv,
                            int n, int chunk) {
    __shared__ int tile[SCAN_T];
    int b = blockIdx.x, t = threadIdx.x;
    int beg = b * chunk, end = min(n, beg + chunk);
    int run = boff[b];
    for (int base = beg; base < end; base += SCAN_T) {
        int i = base + t;
        int creal = (i < end) ? cnt[i] : 0;
        int c = (creal + PAD - 1) & PADM;
        tile[t] = c;
        __syncthreads();
        for (int off = 1; off < SCAN_T; off <<= 1) {
            int v = (t >= off) ? tile[t - off] : 0;
            __syncthreads();
            tile[t] += v;
            __syncthreads();
        }
        if (i < end) {
            rowptr[i] = run + tile[t] - c; // exclusive prefix of padded counts
            float d = (creal == 0) ? 1.0f : (float)creal;
            dinv[i] = rsqrtf(d);
        }
        run += tile[SCAN_T - 1];
        __syncthreads();
    }
    if (b == gridDim.x - 1 && t == 0) rowptr[n] = run;
}

// atomic-free scatter: pos = rowptr[row] + prank (pad slots stay zero from fill_k).
// Plain store — NT store on random 8B writes regressed 65µs (R9).
__global__ void scatter_k(const int* __restrict__ row, const int* __restrict__ col,
                          const float* __restrict__ ea, const float* __restrict__ dinv,
                          const int* __restrict__ rowptr, const int* __restrict__ prank,
                          unsigned long long* __restrict__ cpack, int e) {
    int i = blockIdx.x * blockDim.x + threadIdx.x;
    int stride = gridDim.x * blockDim.x;
    for (; i < e; i += stride) {
        int r = __builtin_nontemporal_load(&row[i]);
        int c = __builtin_nontemporal_load(&col[i]);
        float a = __builtin_nontemporal_load(&ea[i]);
        int pr = __builtin_nontemporal_load(&prank[i]);
        float v = dinv[r] * a * dinv[c];
        int pos = rowptr[r] + pr;
        cpack[pos] = ((unsigned long long)(unsigned)__float_as_int(v) << 32) | (unsigned)c;
    }
}

// out[node][0][:] = x[node][:]  (float4 vectorized)
__global__ void copy_k(const float* __restrict__ x, float* __restrict__ out, int n) {
    int t = blockIdx.x * blockDim.x + threadIdx.x; // n*8 float4s
    if (t < n * 8) {
        int node = t >> 3, q = t & 7;
        ((float4*)out)[(size_t)node * (LSTRIDE / 4) + q] = ((const float4*)x)[t];
    }
}

// one 32-lane group per row; lane = feature; branch-free unroll-8 over pad-8 CSR.
// 8 outstanding gathers/group is the measured MLP sweet spot (R4/R10).
__global__ __launch_bounds__(256) void spmm_k(const int* __restrict__ rowptr,
                                              const unsigned long long* __restrict__ cpack,
                                              const float* __restrict__ pe,
                                              float* __restrict__ out, int n, int layer) {
    int gid = blockIdx.x * 8 + (threadIdx.x >> 5);
    int lane = threadIdx.x & 31;
    if (gid >= n) return;
    float alpha = tanhf(pe[layer]); // BASE_ALPHA = 1
    const float* __restrict__ hsrc = out + (size_t)layer * DF + lane;
    int beg = rowptr[gid], end = rowptr[gid + 1]; // multiple of 8 apart
    float acc = 0.f;
    for (int base = beg; base < end; base += 8) {
        unsigned long long p[8];
#pragma unroll
        for (int u = 0; u < 8; ++u) p[u] = __builtin_nontemporal_load(&cpack[base + u]);
        float h[8];
#pragma unroll
        for (int u = 0; u < 8; ++u)
            h[u] = hsrc[(unsigned)(p[u] & 0xFFFFFFFFu) * (unsigned)LSTRIDE];
#pragma unroll
        for (int u = 0; u < 8; ++u)
            acc = fmaf(__uint_as_float((unsigned)(p[u] >> 32)), h[u], acc);
    }
    out[(size_t)gid * LSTRIDE + (layer + 1) * DF + lane] = alpha * acc;
}

extern "C" void kernel_launch(void* const* d_in, const int* in_sizes, int n_in,
                              void* d_out, int out_size, void* d_ws, size_t ws_size,
                              hipStream_t stream) {
    const float* x  = (const float*)d_in[0];
    const int*   ei = (const int*)d_in[1];
    const float* ea = (const float*)d_in[2];
    const float* pe = (const float*)d_in[3];
    float* out = (float*)d_out;

    const int n = in_sizes[0] / DF;   // 100000
    const int e = in_sizes[2];        // 1600000
    const int* row = ei;
    const int* col = ei + e;

    // workspace layout
    int*   cnt    = (int*)d_ws;               // n  (16B-aligned: ws base)
    int*   rowptr = cnt + n;                  // n+1
    float* dinv   = (float*)(rowptr + n + 1); // n
    int*   bsum   = (int*)(dinv + n);         // SCAN_BLOCKS
    int*   boff   = bsum + SCAN_BLOCKS;       // SCAN_BLOCKS
    int*   prank  = boff + SCAN_BLOCKS;       // e
    size_t off = ((size_t)(prank + e) - (size_t)d_ws + 15) & ~(size_t)15;
    unsigned long long* cpack = (unsigned long long*)((char*)d_ws + off); // e + (PAD-1)n

    const long long cpack_entries = (long long)e + (long long)(PAD - 1) * n;
    const long long cp4 = (cpack_entries * 2 + 3) / 4; // int4 count covering cpack
    const int n4_cnt = (n + 3) / 4;

    const int chunk = (n + SCAN_BLOCKS - 1) / SCAN_BLOCKS;

    fill_k<<<2048, 256, 0, stream>>>(cnt, (int4*)cpack, n4_cnt, cp4);
    hist_k<<<2048, 256, 0, stream>>>(row, cnt, prank, e);
    scan_partial_k<<<SCAN_BLOCKS, SCAN_T, 0, stream>>>(cnt, bsum, n, chunk);
    scan_bsum_k<<<1, SCAN_BLOCKS, 0, stream>>>(bsum, boff);
    scan_emit_k<<<SCAN_BLOCKS, SCAN_T, 0, stream>>>(cnt, boff, rowptr, dinv, n, chunk);
    scatter_k<<<2048, 256, 0, stream>>>(row, col, ea, dinv, rowptr, prank, cpack, e);
    copy_k<<<(n * 8 + 255) / 256, 256, 0, stream>>>(x, out, n);

    for (int L = 0; L < DEPTH; ++L) {
        spmm_k<<<(n + 7) / 8, 256, 0, stream>>>(rowptr, cpack, pe, out, n, L);
    }
}

// Round 12
// 533.070 us; speedup vs baseline: 1.1422x; 1.0019x over previous
//
#include <hip/hip_runtime.h>

#define NN 100000
#define NE 1600000
#define DF 32
#define DEPTH 10
#define LSTRIDE ((DEPTH + 1) * DF) /* 352 floats per node in d_out */
#define SCAN_BLOCKS 256
#define SCAN_T 256
#define PAD 8
#define PADM (~(PAD - 1))

// zero cnt only (0.4MB) — the 19MB cpack fill is replaced by pad_k (R12)
__global__ void zcnt_k(int* __restrict__ cnt, int n4) {
    int i = blockIdx.x * blockDim.x + threadIdx.x;
    if (i < n4) ((int4*)cnt)[i] = make_int4(0, 0, 0, 0);
}

// histogram + per-edge rank within its row (atomic result was free)
__global__ void hist_k(const int* __restrict__ row, int* __restrict__ cnt,
                       int* __restrict__ prank, int e) {
    int i = blockIdx.x * blockDim.x + threadIdx.x;
    int stride = gridDim.x * blockDim.x;
    for (; i < e; i += stride) {
        int r = __builtin_nontemporal_load(&row[i]);
        prank[i] = atomicAdd(&cnt[r], 1);
    }
}

// --- multi-block scan over PADDED counts ((cnt+PAD-1)&PADM) ---
__global__ void scan_partial_k(const int* __restrict__ cnt, int* __restrict__ bsum,
                               int n, int chunk) {
    __shared__ int red[SCAN_T];
    int b = blockIdx.x, t = threadIdx.x;
    int beg = b * chunk, end = min(n, beg + chunk);
    int s = 0;
    for (int i = beg + t; i < end; i += SCAN_T) s += (cnt[i] + PAD - 1) & PADM;
    red[t] = s;
    __syncthreads();
    for (int off = SCAN_T / 2; off; off >>= 1) {
        if (t < off) red[t] += red[t + off];
        __syncthreads();
    }
    if (t == 0) bsum[b] = red[0];
}

__global__ void scan_bsum_k(const int* __restrict__ bsum, int* __restrict__ boff) {
    __shared__ int s[SCAN_BLOCKS];
    int t = threadIdx.x;
    s[t] = bsum[t];
    __syncthreads();
    for (int off = 1; off < SCAN_BLOCKS; off <<= 1) {
        int v = (t >= off) ? s[t - off] : 0;
        __syncthreads();
        s[t] += v;
        __syncthreads();
    }
    boff[t] = (t == 0) ? 0 : s[t - 1];
}

// emit padded-exclusive-prefix rowptr; also compute dinv from real cnt (fused).
__global__ void scan_emit_k(const int* __restrict__ cnt, const int* __restrict__ boff,
                            int* __restrict__ rowptr, float* __restrict__ dinv,
                            int n, int chunk) {
    __shared__ int tile[SCAN_T];
    int b = blockIdx.x, t = threadIdx.x;
    int beg = b * chunk, end = min(n, beg + chunk);
    int run = boff[b];
    for (int base = beg; base < end; base += SCAN_T) {
        int i = base + t;
        int creal = (i < end) ? cnt[i] : 0;
        int c = (creal + PAD - 1) & PADM;
        tile[t] = c;
        __syncthreads();
        for (int off = 1; off < SCAN_T; off <<= 1) {
            int v = (t >= off) ? tile[t - off] : 0;
            __syncthreads();
            tile[t] += v;
            __syncthreads();
        }
        if (i < end) {
            rowptr[i] = run + tile[t] - c; // exclusive prefix of padded counts
            float d = (creal == 0) ? 1.0f : (float)creal;
            dinv[i] = rsqrtf(d);
        }
        run += tile[SCAN_T - 1];
        __syncthreads();
    }
    if (b == gridDim.x - 1 && t == 0) rowptr[n] = run;
}

// zero only the pad slots: [rowptr[r]+cnt[r], rowptr[r+1]) — ~350K entries total,
// adjacent rows adjacent in memory so stores coalesce reasonably.
__global__ void pad_k(const int* __restrict__ rowptr, const int* __restrict__ cnt,
                      unsigned long long* __restrict__ cpack, int n) {
    int r = blockIdx.x * blockDim.x + threadIdx.x;
    if (r < n) {
        int p = rowptr[r] + cnt[r];
        int end = rowptr[r + 1];
        for (; p < end; ++p) cpack[p] = 0ull;
    }
}

// atomic-free scatter: pos = rowptr[row] + prank
__global__ void scatter_k(const int* __restrict__ row, const int* __restrict__ col,
                          const float* __restrict__ ea, const float* __restrict__ dinv,
                          const int* __restrict__ rowptr, const int* __restrict__ prank,
                          unsigned long long* __restrict__ cpack, int e) {
    int i = blockIdx.x * blockDim.x + threadIdx.x;
    int stride = gridDim.x * blockDim.x;
    for (; i < e; i += stride) {
        int r = __builtin_nontemporal_load(&row[i]);
        int c = __builtin_nontemporal_load(&col[i]);
        float a = __builtin_nontemporal_load(&ea[i]);
        int pr = __builtin_nontemporal_load(&prank[i]);
        float v = dinv[r] * a * dinv[c];
        int pos = rowptr[r] + pr;
        cpack[pos] = ((unsigned long long)(unsigned)__float_as_int(v) << 32) | (unsigned)c;
    }
}

// out[node][0][:] = x[node][:]  (float4 vectorized)
__global__ void copy_k(const float* __restrict__ x, float* __restrict__ out, int n) {
    int t = blockIdx.x * blockDim.x + threadIdx.x; // n*8 float4s
    if (t < n * 8) {
        int node = t >> 3, q = t & 7;
        ((float4*)out)[(size_t)node * (LSTRIDE / 4) + q] = ((const float4*)x)[t];
    }
}

// one 32-lane group per row; lane = feature; branch-free unroll-8 over pad-8 CSR.
// 8 outstanding gathers/group is the measured MLP sweet spot (R4/R10).
__global__ __launch_bounds__(256) void spmm_k(const int* __restrict__ rowptr,
                                              const unsigned long long* __restrict__ cpack,
                                              const float* __restrict__ pe,
                                              float* __restrict__ out, int n, int layer) {
    int gid = blockIdx.x * 8 + (threadIdx.x >> 5);
    int lane = threadIdx.x & 31;
    if (gid >= n) return;
    float alpha = tanhf(pe[layer]); // BASE_ALPHA = 1
    const float* __restrict__ hsrc = out + (size_t)layer * DF + lane;
    int beg = rowptr[gid], end = rowptr[gid + 1]; // multiple of 8 apart
    float acc = 0.f;
    for (int base = beg; base < end; base += 8) {
        unsigned long long p[8];
#pragma unroll
        for (int u = 0; u < 8; ++u) p[u] = __builtin_nontemporal_load(&cpack[base + u]);
        float h[8];
#pragma unroll
        for (int u = 0; u < 8; ++u)
            h[u] = hsrc[(unsigned)(p[u] & 0xFFFFFFFFu) * (unsigned)LSTRIDE];
#pragma unroll
        for (int u = 0; u < 8; ++u)
            acc = fmaf(__uint_as_float((unsigned)(p[u] >> 32)), h[u], acc);
    }
    out[(size_t)gid * LSTRIDE + (layer + 1) * DF + lane] = alpha * acc;
}

extern "C" void kernel_launch(void* const* d_in, const int* in_sizes, int n_in,
                              void* d_out, int out_size, void* d_ws, size_t ws_size,
                              hipStream_t stream) {
    const float* x  = (const float*)d_in[0];
    const int*   ei = (const int*)d_in[1];
    const float* ea = (const float*)d_in[2];
    const float* pe = (const float*)d_in[3];
    float* out = (float*)d_out;

    const int n = in_sizes[0] / DF;   // 100000
    const int e = in_sizes[2];        // 1600000
    const int* row = ei;
    const int* col = ei + e;

    // workspace layout
    int*   cnt    = (int*)d_ws;               // n  (16B-aligned: ws base)
    int*   rowptr = cnt + n;                  // n+1
    float* dinv   = (float*)(rowptr + n + 1); // n
    int*   bsum   = (int*)(dinv + n);         // SCAN_BLOCKS
    int*   boff   = bsum + SCAN_BLOCKS;       // SCAN_BLOCKS
    int*   prank  = boff + SCAN_BLOCKS;       // e
    size_t off = ((size_t)(prank + e) - (size_t)d_ws + 15) & ~(size_t)15;
    unsigned long long* cpack = (unsigned long long*)((char*)d_ws + off); // e + (PAD-1)n

    const int n4_cnt = (n + 3) / 4;
    const int chunk = (n + SCAN_BLOCKS - 1) / SCAN_BLOCKS;

    zcnt_k<<<(n4_cnt + 255) / 256, 256, 0, stream>>>(cnt, n4_cnt);
    hist_k<<<2048, 256, 0, stream>>>(row, cnt, prank, e);
    scan_partial_k<<<SCAN_BLOCKS, SCAN_T, 0, stream>>>(cnt, bsum, n, chunk);
    scan_bsum_k<<<1, SCAN_BLOCKS, 0, stream>>>(bsum, boff);
    scan_emit_k<<<SCAN_BLOCKS, SCAN_T, 0, stream>>>(cnt, boff, rowptr, dinv, n, chunk);
    pad_k<<<(n + 255) / 256, 256, 0, stream>>>(rowptr, cnt, cpack, n);
    scatter_k<<<2048, 256, 0, stream>>>(row, col, ea, dinv, rowptr, prank, cpack, e);
    copy_k<<<(n * 8 + 255) / 256, 256, 0, stream>>>(x, out, n);

    for (int L = 0; L < DEPTH; ++L) {
        spmm_k<<<(n + 7) / 8, 256, 0, stream>>>(rowptr, cpack, pe, out, n, L);
    }
}